// Round 4
// baseline (33.160 us; speedup 1.0000x reference)
//
#include <hip/hip_runtime.h>

// y[b,o,h,w] = sum_j alphas[o,j] * x[b,j,(128-h)&127,(128-w)&127]
// (FFT2 -> complex channel mix -> IFFT2 collapses to flipped-input channel GEMM;
//  betas contributes only to the imaginary part and drops out.)
//
// D[w][o] = sum_k X[w][k] * alphas[o][k]; flip applied at input staging.
// LDS holds ONLY the X tile (32 KB) -> 4 blocks/CU, all 1024 blocks co-resident.
// Alphas live as per-wave MFMA B-fragments in registers (32 VGPR), loaded once
// per block from global (64 KB, L2-resident across blocks).

using bf16   = __bf16;
using bf16x4 = __attribute__((ext_vector_type(4))) __bf16;
using bf16x8 = __attribute__((ext_vector_type(8))) __bf16;
using f32x4  = __attribute__((ext_vector_type(4))) float;

static __device__ __forceinline__ float f4c(const float4& v, int i) {
    switch (i) { case 0: return v.x; case 1: return v.y; case 2: return v.z; default: return v.w; }
}

// X LDS layout: quad-row q = k>>2 (1024 B each); bf16x4 for (q, w) at
//   q*1024 + ((w*8 | (k&3)*2) ^ swz),  swz = (((q>>1)&3) ^ ((w>>4)&3)) << 3.
// (q>>1)-term spreads the 4 g-groups of an A-frag read (q = 8*ks+2g) over
// distinct bank groups; (w>>4)-term spreads staging writes (w stride 4 within
// an instruction) over 16 banks. XOR touches only byte bits 3-4, bijective.
static __device__ __forceinline__ int xoff(int k, int w) {
    const int q   = k >> 2;
    const int swz = ((((q >> 1) & 3) ^ ((w >> 4) & 3)) << 3);
    return q * 1024 + (((w * 8) | ((k & 3) * 2)) ^ swz);
}

__global__ __launch_bounds__(256, 4)
void kk_freqmix_kernel(const float* __restrict__ x,
                       const float* __restrict__ alphas,
                       float* __restrict__ out)
{
    __shared__ unsigned char ldsX[32768];

    const int t   = threadIdx.x;
    const int bid = blockIdx.x;
    const int b   = bid >> 7;           // batch
    const int h   = bid & 127;          // OUTPUT row
    const int hs  = (128 - h) & 127;    // source row in x (h-flip)

    const int l  = t & 63;
    const int wv = t >> 6;    // wave 0..3 owns o-slice [wv*32, wv*32+32)
    const int g  = l >> 4;    // lane quadrant (k-chunk selector)
    const int lr = l & 15;

    // ---- stage x[b, :, hs, :] (fp32 -> bf16) into LDS with w-flip ----
    const float* xrow = x + ((size_t)b * 128 * 16384) + (size_t)hs * 128;
    #pragma unroll
    for (int it = 0; it < 4; ++it) {
        const int p  = it * 256 + t;
        const int q  = p >> 5;            // k-quad 0..31
        const int n0 = (p & 31) * 4;      // source w base
        const float4 xv0 = *(const float4*)(xrow + (size_t)(4*q + 0) * 16384 + n0);
        const float4 xv1 = *(const float4*)(xrow + (size_t)(4*q + 1) * 16384 + n0);
        const float4 xv2 = *(const float4*)(xrow + (size_t)(4*q + 2) * 16384 + n0);
        const float4 xv3 = *(const float4*)(xrow + (size_t)(4*q + 3) * 16384 + n0);
        #pragma unroll
        for (int i = 0; i < 4; ++i) {
            const int wd = (128 - (n0 + i)) & 127;   // w-flip at input
            bf16x4 v;
            v[0]=(bf16)f4c(xv0,i); v[1]=(bf16)f4c(xv1,i);
            v[2]=(bf16)f4c(xv2,i); v[3]=(bf16)f4c(xv3,i);
            *(bf16x4*)(ldsX + xoff(4*q, wd)) = v;
        }
    }

    // ---- alphas B-fragments straight to registers (fp32 -> bf16) ----
    // bfr[nf][ks]: lane holds alphas[o][k0..k0+8), o = wv*32+nf*16+lr,
    // k0 = ks*32+g*8 -- same sigma(g,v)=g*8+v as the A-side.
    bf16x8 bfr[2][4];
    #pragma unroll
    for (int nf = 0; nf < 2; ++nf) {
        const int o = wv * 32 + nf * 16 + lr;
        #pragma unroll
        for (int ks = 0; ks < 4; ++ks) {
            const int k0 = ks * 32 + g * 8;
            const float4 a0 = *(const float4*)(alphas + o * 128 + k0);
            const float4 a1 = *(const float4*)(alphas + o * 128 + k0 + 4);
            bf16x8 v;
            v[0]=(bf16)a0.x; v[1]=(bf16)a0.y; v[2]=(bf16)a0.z; v[3]=(bf16)a0.w;
            v[4]=(bf16)a1.x; v[5]=(bf16)a1.y; v[6]=(bf16)a1.z; v[7]=(bf16)a1.w;
            bfr[nf][ks] = v;
        }
    }

    __syncthreads();

    // ---- MFMA: D[w][o] = sum_k X[w][k] * alphas[o][k] ----
    f32x4 acc[8][2];          // [mf = w-tile][nf = o-tile]
    #pragma unroll
    for (int mf = 0; mf < 8; ++mf)
        #pragma unroll
        for (int nf = 0; nf < 2; ++nf)
            acc[mf][nf] = (f32x4){0.f, 0.f, 0.f, 0.f};

    #pragma unroll
    for (int ks = 0; ks < 4; ++ks) {
        const int k0 = ks * 32 + g * 8;
        #pragma unroll
        for (int mf = 0; mf < 8; ++mf) {
            const int w = mf * 16 + lr;
            const unsigned char* base = ldsX + xoff(k0, w);
            const bf16x4 lo = *(const bf16x4*)(base);
            const bf16x4 hi = *(const bf16x4*)(base + 1024);
            bf16x8 a;
            a[0]=lo[0]; a[1]=lo[1]; a[2]=lo[2]; a[3]=lo[3];
            a[4]=hi[0]; a[5]=hi[1]; a[6]=hi[2]; a[7]=hi[3];
            acc[mf][0] = __builtin_amdgcn_mfma_f32_16x16x32_bf16(a, bfr[0][ks], acc[mf][0], 0, 0, 0);
            acc[mf][1] = __builtin_amdgcn_mfma_f32_16x16x32_bf16(a, bfr[1][ks], acc[mf][1], 0, 0, 0);
        }
    }

    // ---- epilogue: plain float4 stores (full 64B lines per instruction) ----
    // C/D layout: col(o) = lane&15, row(w) = (lane>>4)*4 + reg -> lane holds 4
    // consecutive w at fixed o; g=0..3 at same lr cover 16 floats = 64B.
    float* const outb = out + ((size_t)b * 128 * 16384) + (size_t)h * 128;
    #pragma unroll
    for (int mf = 0; mf < 8; ++mf) {
        const int w0 = mf * 16 + g * 4;
        #pragma unroll
        for (int nf = 0; nf < 2; ++nf) {
            const int o = wv * 32 + nf * 16 + lr;
            *(f32x4*)(outb + (size_t)o * 16384 + w0) = acc[mf][nf];
        }
    }
}

extern "C" void kernel_launch(void* const* d_in, const int* in_sizes, int n_in,
                              void* d_out, int out_size, void* d_ws, size_t ws_size,
                              hipStream_t stream) {
    const float* x      = (const float*)d_in[0];
    const float* alphas = (const float*)d_in[1];
    // betas (d_in[2]) provably unused: contributes only to Im(y), dropped by real().
    float* out = (float*)d_out;

    dim3 grid(1024);   // one block per (b, h_out): 8 * 128
    dim3 block(256);
    hipLaunchKernelGGL(kk_freqmix_kernel, grid, block, 0, stream, x, alphas, out);
}

// Round 5
// 30.586 us; speedup vs baseline: 1.0841x; 1.0841x over previous
//
#include <hip/hip_runtime.h>

// y[b,o,h,w] = sum_j alphas[o,j] * x[b,j,(128-h)&127,(128-w)&127]
// (FFT2 -> complex channel mix -> IFFT2 collapses to flipped-input channel GEMM;
//  betas contributes only to the imaginary part and drops out.)
//
// D[w][o] = sum_k X[w][k] * alphas[o][k]; flip applied at input staging.
// Pipelined: grid 512, 2 tiles/block, double-buffered 2x32KB LDS (64KB ->
// 2 blocks/CU). Tile t+1's global loads are issued before tile t's compute
// (T14 async-STAGE split); tile t's stores overlap tile t+1's compute.

using bf16   = __bf16;
using bf16x4 = __attribute__((ext_vector_type(4))) __bf16;
using bf16x8 = __attribute__((ext_vector_type(8))) __bf16;
using f32x4  = __attribute__((ext_vector_type(4))) float;

static __device__ __forceinline__ float f4c(const float4& v, int i) {
    switch (i) { case 0: return v.x; case 1: return v.y; case 2: return v.z; default: return v.w; }
}

// X LDS layout: quad-row q = k>>2 (1024 B each); bf16x4 for (q, w) at
//   q*1024 + ((w*8 | (k&3)*2) ^ swz),  swz = (((q>>1)&3) ^ ((w>>4)&3)) << 3.
// (q>>1)-term spreads the 4 g-groups of an A-frag read over distinct bank
// groups; (w>>4)-term spreads staging writes over 16 banks. Bits 3-4 only,
// bijective per row. (Round-3 counters: 131072 conflicts/dispatch ~ free.)
static __device__ __forceinline__ int xoff(int k, int w) {
    const int q   = k >> 2;
    const int swz = ((((q >> 1) & 3) ^ ((w >> 4) & 3)) << 3);
    return q * 1024 + (((w * 8) | ((k & 3) * 2)) ^ swz);
}

static __device__ __forceinline__ void load_x(const float* __restrict__ xrow, int t,
                                              float4 R[4][4]) {
    #pragma unroll
    for (int it = 0; it < 4; ++it) {
        const int p  = it * 256 + t;
        const int q  = p >> 5;
        const int n0 = (p & 31) * 4;
        #pragma unroll
        for (int r = 0; r < 4; ++r)
            R[it][r] = *(const float4*)(xrow + (size_t)(4 * q + r) * 16384 + n0);
    }
}

static __device__ __forceinline__ void write_x(const float4 R[4][4], int t,
                                               unsigned char* __restrict__ buf) {
    #pragma unroll
    for (int it = 0; it < 4; ++it) {
        const int p  = it * 256 + t;
        const int q  = p >> 5;
        const int n0 = (p & 31) * 4;
        #pragma unroll
        for (int i = 0; i < 4; ++i) {
            const int wd = (128 - (n0 + i)) & 127;   // w-flip at input
            bf16x4 v;
            v[0] = (bf16)f4c(R[it][0], i); v[1] = (bf16)f4c(R[it][1], i);
            v[2] = (bf16)f4c(R[it][2], i); v[3] = (bf16)f4c(R[it][3], i);
            *(bf16x4*)(buf + xoff(4 * q, wd)) = v;
        }
    }
}

static __device__ __forceinline__ void compute_tile(const unsigned char* __restrict__ buf,
                                                    const bf16x8 bfr[2][4],
                                                    int lr, int g, f32x4 acc[8][2]) {
    #pragma unroll
    for (int mf = 0; mf < 8; ++mf)
        #pragma unroll
        for (int nf = 0; nf < 2; ++nf)
            acc[mf][nf] = (f32x4){0.f, 0.f, 0.f, 0.f};
    #pragma unroll
    for (int ks = 0; ks < 4; ++ks) {
        const int k0 = ks * 32 + g * 8;   // sigma(g,v) = g*8+v, same as B-side
        #pragma unroll
        for (int mf = 0; mf < 8; ++mf) {
            const int w = mf * 16 + lr;
            const unsigned char* base = buf + xoff(k0, w);
            const bf16x4 lo = *(const bf16x4*)(base);
            const bf16x4 hi = *(const bf16x4*)(base + 1024);   // q even -> same swz
            bf16x8 a;
            a[0]=lo[0]; a[1]=lo[1]; a[2]=lo[2]; a[3]=lo[3];
            a[4]=hi[0]; a[5]=hi[1]; a[6]=hi[2]; a[7]=hi[3];
            acc[mf][0] = __builtin_amdgcn_mfma_f32_16x16x32_bf16(a, bfr[0][ks], acc[mf][0], 0, 0, 0);
            acc[mf][1] = __builtin_amdgcn_mfma_f32_16x16x32_bf16(a, bfr[1][ks], acc[mf][1], 0, 0, 0);
        }
    }
}

// C/D layout: col(o) = lane&15, row(w) = (lane>>4)*4 + reg -> lane holds 4
// consecutive w at fixed o; g=0..3 at same lr cover 16 floats = 64B lines.
static __device__ __forceinline__ void store_tile(float* __restrict__ outb,
                                                  int wv, int lr, int g,
                                                  const f32x4 acc[8][2]) {
    #pragma unroll
    for (int mf = 0; mf < 8; ++mf) {
        const int w0 = mf * 16 + g * 4;
        #pragma unroll
        for (int nf = 0; nf < 2; ++nf) {
            const int o = wv * 32 + nf * 16 + lr;
            *(f32x4*)(outb + (size_t)o * 16384 + w0) = acc[mf][nf];
        }
    }
}

__global__ __launch_bounds__(256, 2)
void kk_freqmix_kernel(const float* __restrict__ x,
                       const float* __restrict__ alphas,
                       float* __restrict__ out)
{
    __shared__ unsigned char ldsX[2][32768];

    const int t   = threadIdx.x;
    const int bid = blockIdx.x;
    const int l  = t & 63;
    const int wv = t >> 6;
    const int g  = l >> 4;
    const int lr = l & 15;

    // Two consecutive tiles (same b, adjacent h -> adjacent source rows).
    const int tA = bid * 2, tB = tA + 1;
    const int bA = tA >> 7, hA = tA & 127, hsA = (128 - hA) & 127;
    const int hB = tB & 127, hsB = (128 - hB) & 127;
    const float* xrowA = x + (size_t)bA * 2097152 + (size_t)hsA * 128;
    const float* xrowB = x + (size_t)bA * 2097152 + (size_t)hsB * 128;
    float* const outA  = out + (size_t)bA * 2097152 + (size_t)hA * 128;
    float* const outB  = out + (size_t)bA * 2097152 + (size_t)hB * 128;

    float4 R[4][4];

    // ---- prologue: issue tile-A loads, then alphas (latency overlaps) ----
    load_x(xrowA, t, R);

    // alphas B-fragments: lane holds alphas[o][k0..k0+8), o = wv*32+nf*16+lr,
    // k0 = ks*32+g*8. 64KB/block from L2/L3, once, hoisted out of everything.
    bf16x8 bfr[2][4];
    #pragma unroll
    for (int nf = 0; nf < 2; ++nf) {
        const int o = wv * 32 + nf * 16 + lr;
        #pragma unroll
        for (int ks = 0; ks < 4; ++ks) {
            const int k0 = ks * 32 + g * 8;
            const float4 a0 = *(const float4*)(alphas + o * 128 + k0);
            const float4 a1 = *(const float4*)(alphas + o * 128 + k0 + 4);
            bf16x8 v;
            v[0]=(bf16)a0.x; v[1]=(bf16)a0.y; v[2]=(bf16)a0.z; v[3]=(bf16)a0.w;
            v[4]=(bf16)a1.x; v[5]=(bf16)a1.y; v[6]=(bf16)a1.z; v[7]=(bf16)a1.w;
            bfr[nf][ks] = v;
        }
    }

    write_x(R, t, ldsX[0]);
    __syncthreads();

    f32x4 acc[8][2];

    // ---- iter 0: prefetch B || compute A ----
    load_x(xrowB, t, R);                  // issue early; latency under MFMA
    compute_tile(ldsX[0], bfr, lr, g, acc);
    write_x(R, t, ldsX[1]);               // vmcnt-gated, lands after compute
    __syncthreads();

    // ---- iter 1: store A (overlaps) || compute B, then store B ----
    store_tile(outA, wv, lr, g, acc);
    compute_tile(ldsX[1], bfr, lr, g, acc);
    store_tile(outB, wv, lr, g, acc);
}

extern "C" void kernel_launch(void* const* d_in, const int* in_sizes, int n_in,
                              void* d_out, int out_size, void* d_ws, size_t ws_size,
                              hipStream_t stream) {
    const float* x      = (const float*)d_in[0];
    const float* alphas = (const float*)d_in[1];
    // betas (d_in[2]) provably unused: contributes only to Im(y), dropped by real().
    float* out = (float*)d_out;

    dim3 grid(512);    // 2 tiles per block: 8 * 128 / 2
    dim3 block(256);
    hipLaunchKernelGGL(kk_freqmix_kernel, grid, block, 0, stream, x, alphas, out);
}

// Round 6
// 29.517 us; speedup vs baseline: 1.1234x; 1.0362x over previous
//
#include <hip/hip_runtime.h>

// y[b,o,h,w] = sum_j alphas[o,j] * x[b,j,(128-h)&127,(128-w)&127]
// (FFT2 -> complex channel mix -> IFFT2 collapses to flipped-input channel GEMM;
//  betas contributes only to the imaginary part and drops out.)
//
// D[w][o] = sum_k X[w][k] * alphas[o][k]; flip applied at input staging.
// 512 threads/block (8 waves, each owns a 16-wide o-slice), one (b,h) tile per
// block, single 32KB LDS X tile -> 2 blocks/CU = 4 waves/SIMD, grid 1024 =
// 2 dispatch generations (cross-block stagger for read/write overlap).

using bf16   = __bf16;
using bf16x4 = __attribute__((ext_vector_type(4))) __bf16;
using bf16x8 = __attribute__((ext_vector_type(8))) __bf16;
using f32x4  = __attribute__((ext_vector_type(4))) float;

static __device__ __forceinline__ float f4c(const float4& v, int i) {
    switch (i) { case 0: return v.x; case 1: return v.y; case 2: return v.z; default: return v.w; }
}

// X LDS layout: quad-row q = k>>2 (1024 B each); bf16x4 for (q, w) at
//   q*1024 + ((w*8 | (k&3)*2) ^ swz),  swz = (((q>>1)&3) ^ ((w>>4)&3)) << 3.
// (q>>1)-term spreads A-frag g-groups across bank-groups; (w>>4)-term spreads
// staging writes. XOR touches byte bits 3-4 only, bijective per row.
// (Measured round 3: 131072 conflict-cycles/dispatch ~ negligible.)
static __device__ __forceinline__ int xoff(int k, int w) {
    const int q   = k >> 2;
    const int swz = ((((q >> 1) & 3) ^ ((w >> 4) & 3)) << 3);
    return q * 1024 + (((w * 8) | ((k & 3) * 2)) ^ swz);
}

__global__ __launch_bounds__(512, 4)
void kk_freqmix_kernel(const float* __restrict__ x,
                       const float* __restrict__ alphas,
                       float* __restrict__ out)
{
    __shared__ unsigned char ldsX[32768];

    const int t   = threadIdx.x;       // 0..511
    const int bid = blockIdx.x;
    const int b   = bid >> 7;           // batch
    const int h   = bid & 127;          // OUTPUT row
    const int hs  = (128 - h) & 127;    // source row in x (h-flip)

    const int l  = t & 63;
    const int wv = t >> 6;    // wave 0..7 owns o-slice [wv*16, wv*16+16)
    const int g  = l >> 4;    // lane quadrant (k-chunk selector)
    const int lr = l & 15;

    const float* xrow = x + (size_t)b * 2097152 + (size_t)hs * 128;

    // ---- issue alphas loads first (latency hides under x staging) ----
    // Lane needs alphas[o][ks*32+g*8 .. +8), o = wv*16 + lr.
    const int o_own = wv * 16 + lr;
    float4 arw[4][2];
    #pragma unroll
    for (int ks = 0; ks < 4; ++ks) {
        const int k0 = ks * 32 + g * 8;
        arw[ks][0] = *(const float4*)(alphas + o_own * 128 + k0);
        arw[ks][1] = *(const float4*)(alphas + o_own * 128 + k0 + 4);
    }

    // ---- stage x[b, :, hs, :] (fp32 -> bf16) into LDS with w-flip ----
    // 1024 items of (4 k-rows x 4 w); 512 threads -> 2 items each.
    #pragma unroll
    for (int it = 0; it < 2; ++it) {
        const int j  = it * 512 + t;
        const int q  = j >> 5;            // k-quad 0..31
        const int n0 = (j & 31) * 4;      // source w base
        float4 R0 = *(const float4*)(xrow + (size_t)(4*q + 0) * 16384 + n0);
        float4 R1 = *(const float4*)(xrow + (size_t)(4*q + 1) * 16384 + n0);
        float4 R2 = *(const float4*)(xrow + (size_t)(4*q + 2) * 16384 + n0);
        float4 R3 = *(const float4*)(xrow + (size_t)(4*q + 3) * 16384 + n0);
        #pragma unroll
        for (int i = 0; i < 4; ++i) {
            const int wd = (128 - (n0 + i)) & 127;   // w-flip at input
            bf16x4 v;
            v[0] = (bf16)f4c(R0, i); v[1] = (bf16)f4c(R1, i);
            v[2] = (bf16)f4c(R2, i); v[3] = (bf16)f4c(R3, i);
            *(bf16x4*)(ldsX + xoff(4 * q, wd)) = v;
        }
    }

    // ---- convert alphas to MFMA B-fragments (16 VGPR) ----
    bf16x8 bfr[4];
    #pragma unroll
    for (int ks = 0; ks < 4; ++ks) {
        bf16x8 v;
        v[0]=(bf16)arw[ks][0].x; v[1]=(bf16)arw[ks][0].y;
        v[2]=(bf16)arw[ks][0].z; v[3]=(bf16)arw[ks][0].w;
        v[4]=(bf16)arw[ks][1].x; v[5]=(bf16)arw[ks][1].y;
        v[6]=(bf16)arw[ks][1].z; v[7]=(bf16)arw[ks][1].w;
        bfr[ks] = v;
    }

    __syncthreads();

    // ---- MFMA: D[w][o] = sum_k X[w][k] * alphas[o][k], o-slice per wave ----
    f32x4 acc[8];             // mf = w-tile index
    #pragma unroll
    for (int mf = 0; mf < 8; ++mf)
        acc[mf] = (f32x4){0.f, 0.f, 0.f, 0.f};

    #pragma unroll
    for (int ks = 0; ks < 4; ++ks) {
        const int k0 = ks * 32 + g * 8;   // sigma(g,v) = g*8+v, same as B-side
        #pragma unroll
        for (int mf = 0; mf < 8; ++mf) {
            const int w = mf * 16 + lr;
            const unsigned char* base = ldsX + xoff(k0, w);
            const bf16x4 lo = *(const bf16x4*)(base);
            const bf16x4 hi = *(const bf16x4*)(base + 1024);   // q even -> same swz
            bf16x8 a;
            a[0]=lo[0]; a[1]=lo[1]; a[2]=lo[2]; a[3]=lo[3];
            a[4]=hi[0]; a[5]=hi[1]; a[6]=hi[2]; a[7]=hi[3];
            acc[mf] = __builtin_amdgcn_mfma_f32_16x16x32_bf16(a, bfr[ks], acc[mf], 0, 0, 0);
        }
    }

    // ---- epilogue: plain float4 stores (full 64B lines per instruction) ----
    // C/D: col(o) = lane&15 -> o = wv*16+lr; row(w) = (lane>>4)*4 + reg.
    float* const outb = out + (size_t)b * 2097152 + (size_t)h * 128;
    #pragma unroll
    for (int mf = 0; mf < 8; ++mf) {
        const int w0 = mf * 16 + g * 4;
        *(f32x4*)(outb + (size_t)o_own * 16384 + w0) = acc[mf];
    }
}

extern "C" void kernel_launch(void* const* d_in, const int* in_sizes, int n_in,
                              void* d_out, int out_size, void* d_ws, size_t ws_size,
                              hipStream_t stream) {
    const float* x      = (const float*)d_in[0];
    const float* alphas = (const float*)d_in[1];
    // betas (d_in[2]) provably unused: contributes only to Im(y), dropped by real().
    float* out = (float*)d_out;

    dim3 grid(1024);   // one block per (b, h_out)
    dim3 block(512);
    hipLaunchKernelGGL(kk_freqmix_kernel, grid, block, 0, stream, x, alphas, out);
}

// Round 7
// 28.738 us; speedup vs baseline: 1.1539x; 1.0271x over previous
//
#include <hip/hip_runtime.h>

// y[b,o,h,w] = sum_j alphas[o,j] * x[b,j,(128-h)&127,(128-w)&127]
// (FFT2 -> complex channel mix -> IFFT2 collapses to flipped-input channel GEMM;
//  betas contributes only to the imaginary part and drops out.)
//
// Barrier-free streaming design: NO X tile in LDS. Each wave owns one
// (b, h, 16-wide w-chunk) and computes all 128 output channels:
//   D[o][w] = sum_k alphas[o][k] * X[k][w]   (A=alphas frags from LDS,
//   B=X frags via 8 scalar global loads per k-group, 4 full 64B lines/instr).
// Only one tiny barrier (after 32KB alphas staging); afterwards 8192 resident
// waves stream loads/MFMA/stores independently -- no phase convoy.

using bf16   = __bf16;
using bf16x8 = __attribute__((ext_vector_type(8))) __bf16;
using f32x4  = __attribute__((ext_vector_type(4))) float;

// alphas LDS: bf16 [o][k], 256 B rows, 16B-granule XOR swizzle:
//   byte(o,k) = o*256 + (k*2 ^ ((o&7)<<4))
// Frag reads (lanes: o=mf*16+lr, k0=ks*32+g*8): bank-quad = 4*(((ks*4+g)^(lr&7))&7)
// -> each quad hit by exactly 8 lanes = conflict-free floor. Staging writes
// likewise uniform.
static __device__ __forceinline__ int aoff(int o, int k) {
    return o * 256 + ((k * 2) ^ ((o & 7) << 4));
}

__global__ __launch_bounds__(512, 4)
void kk_freqmix_kernel(const float* __restrict__ x,
                       const float* __restrict__ alphas,
                       float* __restrict__ out)
{
    __shared__ unsigned char ldsA[32768];

    const int t   = threadIdx.x;        // 0..511
    const int bid = blockIdx.x;
    const int b   = bid >> 7;           // batch
    const int h   = bid & 127;          // OUTPUT row
    const int hs  = (128 - h) & 127;    // source row in x (h-flip)

    const int l  = t & 63;
    const int wc = t >> 6;              // wave 0..7 owns w-chunk [wc*16, wc*16+16)
    const int g  = l >> 4;              // k-slice selector
    const int lr = l & 15;

    const int w  = wc * 16 + lr;        // output column this lane produces
    const int ws = (128 - w) & 127;     // source column (w-flip at load)
    const float* xcol = x + (size_t)b * 2097152 + (size_t)hs * 128 + ws;

    // ---- issue first x k-group (ks=0) immediately: deepest-latency loads ----
    float xv0[8], xv1[8];
    #pragma unroll
    for (int v = 0; v < 8; ++v)
        xv0[v] = xcol[(g * 8 + v) * 16384];

    // ---- stage alphas (64KB fp32 -> 32KB bf16 LDS), coalesced, once/block ----
    {
        const int o   = t >> 2;         // 0..127
        const int seg = t & 3;          // 32-wide k segment
        const float* ap = alphas + o * 128 + seg * 32;
        #pragma unroll
        for (int j = 0; j < 4; ++j) {
            const float4 a0 = *(const float4*)(ap + j * 8);
            const float4 a1 = *(const float4*)(ap + j * 8 + 4);
            bf16x8 vv;
            vv[0]=(bf16)a0.x; vv[1]=(bf16)a0.y; vv[2]=(bf16)a0.z; vv[3]=(bf16)a0.w;
            vv[4]=(bf16)a1.x; vv[5]=(bf16)a1.y; vv[6]=(bf16)a1.z; vv[7]=(bf16)a1.w;
            *(bf16x8*)(ldsA + aoff(o, seg * 32 + j * 8)) = vv;
        }
    }
    __syncthreads();   // the ONLY barrier; x ks=0 latency hid under staging

    // ---- k-loop: rotating one-ahead prefetch of x k-groups ----
    f32x4 acc[8];
    #pragma unroll
    for (int mf = 0; mf < 8; ++mf) acc[mf] = (f32x4){0.f, 0.f, 0.f, 0.f};

    #pragma unroll
    for (int ks = 0; ks < 4; ++ks) {
        if (ks < 3) {
            #pragma unroll
            for (int v = 0; v < 8; ++v)
                xv1[v] = xcol[((ks + 1) * 32 + g * 8 + v) * 16384];
        }
        bf16x8 bfrag;                    // B[k][w]: lane(g,lr) holds k0+g*8+v
        #pragma unroll
        for (int v = 0; v < 8; ++v) bfrag[v] = (bf16)xv0[v];

        const int k0 = ks * 32 + g * 8;  // same sigma(g,v)=g*8+v on A and B
        #pragma unroll
        for (int mf = 0; mf < 8; ++mf) {
            const bf16x8 afrag = *(const bf16x8*)(ldsA + aoff(mf * 16 + lr, k0));
            acc[mf] = __builtin_amdgcn_mfma_f32_16x16x32_bf16(afrag, bfrag, acc[mf], 0, 0, 0);
        }
        #pragma unroll
        for (int v = 0; v < 8; ++v) xv0[v] = xv1[v];   // renamed away by unroll
    }

    // ---- stores: D col(w)=lane&15, row(o)=g*4+r (round-1-verified layout) ----
    // 16 lanes x 4B contiguous per (mf,r) -> every 64B out line written fully.
    float* const op = out + (size_t)b * 2097152 + (size_t)h * 128 + w;
    #pragma unroll
    for (int mf = 0; mf < 8; ++mf) {
        #pragma unroll
        for (int r = 0; r < 4; ++r)
            op[(size_t)(mf * 16 + g * 4 + r) * 16384] = acc[mf][r];
    }
}

extern "C" void kernel_launch(void* const* d_in, const int* in_sizes, int n_in,
                              void* d_out, int out_size, void* d_ws, size_t ws_size,
                              hipStream_t stream) {
    const float* x      = (const float*)d_in[0];
    const float* alphas = (const float*)d_in[1];
    // betas (d_in[2]) provably unused: contributes only to Im(y), dropped by real().
    float* out = (float*)d_out;

    dim3 grid(1024);   // one block per (b, h_out); 8 waves = 8 w-chunks each
    dim3 block(512);
    hipLaunchKernelGGL(kk_freqmix_kernel, grid, block, 0, stream, x, alphas, out);
}

// Round 8
// 28.295 us; speedup vs baseline: 1.1719x; 1.0157x over previous
//
#include <hip/hip_runtime.h>

// y[b,o,h,w] = sum_j alphas[o,j] * x[b,j,(128-h)&127,(128-w)&127]
// (FFT2 -> complex channel mix -> IFFT2 collapses to flipped-input channel GEMM;
//  betas contributes only to the imaginary part and drops out.)
//
// Barrier-free streaming (round-7 structure, verified) + deep pipeline:
//  - each wave owns (b, h, 16-wide w-chunk), computes all 128 o channels
//  - A-frags from a 32KB swizzled alphas LDS (staged ONCE per block)
//  - B-frags via scalar global loads, 2 k-groups (16 loads, 4KB/wave) in
//    flight at all times; parity double-buffer, consume s -> issue s+2
//  - persistent blocks: grid 512 = residency capacity, 2 tiles/block; tile
//    B's loads issue under tile A's MFMA+stores, stream never drains.

using bf16   = __bf16;
using bf16x8 = __attribute__((ext_vector_type(8))) __bf16;
using f32x4  = __attribute__((ext_vector_type(4))) float;

// alphas LDS: bf16 [o][k], 256 B rows, 16B-granule XOR swizzle:
//   byte(o,k) = o*256 + (k*2 ^ ((o&7)<<4))
// Frag reads (o=mf*16+lr, k0=ks*32+g*8) hit each bank-quad with exactly 8
// lanes (conflict-free floor); staging writes likewise uniform. (Round 7: OK.)
static __device__ __forceinline__ int aoff(int o, int k) {
    return o * 256 + ((k * 2) ^ ((o & 7) << 4));
}

__global__ __launch_bounds__(512, 4)
void kk_freqmix_kernel(const float* __restrict__ x,
                       const float* __restrict__ alphas,
                       float* __restrict__ out)
{
    __shared__ unsigned char ldsA[32768];

    const int t   = threadIdx.x;        // 0..511
    const int bid = blockIdx.x;         // 0..511 (persistent, 2 tiles each)

    const int l  = t & 63;
    const int wc = t >> 6;              // wave 0..7 owns w-chunk [wc*16, +16)
    const int g  = l >> 4;              // k-slice selector
    const int lr = l & 15;
    const int w  = wc * 16 + lr;        // output column this lane produces
    const int ws = (128 - w) & 127;     // source column (w-flip at load)

    // Two consecutive tiles; tA even -> both share batch bb.
    const int tA  = bid * 2;
    const int bb  = tA >> 7;
    const int hA  = tA & 127,          hB  = (tA + 1) & 127;
    const int hsA = (128 - hA) & 127,  hsB = (128 - hB) & 127;

    const float* xcol[2] = {
        x + (size_t)bb * 2097152 + (size_t)hsA * 128 + ws,
        x + (size_t)bb * 2097152 + (size_t)hsB * 128 + ws };
    float* const outp[2] = {
        out + (size_t)bb * 2097152 + (size_t)hA * 128 + w,
        out + (size_t)bb * 2097152 + (size_t)hB * 128 + w };

    // ---- pipeline prologue: issue steps 0,1 (tile A, ks 0..1) = 16 loads ----
    float xv[2][8];
    #pragma unroll
    for (int v = 0; v < 8; ++v) xv[0][v] = xcol[0][(     g * 8 + v) * 16384];
    #pragma unroll
    for (int v = 0; v < 8; ++v) xv[1][v] = xcol[0][(32 + g * 8 + v) * 16384];

    // ---- stage alphas (64KB fp32 -> 32KB bf16 LDS), once per block ----
    {
        const int o   = t >> 2;         // 0..127
        const int seg = t & 3;          // 32-wide k segment
        const float* ap = alphas + o * 128 + seg * 32;
        #pragma unroll
        for (int j = 0; j < 4; ++j) {
            const float4 a0 = *(const float4*)(ap + j * 8);
            const float4 a1 = *(const float4*)(ap + j * 8 + 4);
            bf16x8 vv;
            vv[0]=(bf16)a0.x; vv[1]=(bf16)a0.y; vv[2]=(bf16)a0.z; vv[3]=(bf16)a0.w;
            vv[4]=(bf16)a1.x; vv[5]=(bf16)a1.y; vv[6]=(bf16)a1.z; vv[7]=(bf16)a1.w;
            *(bf16x8*)(ldsA + aoff(o, seg * 32 + j * 8)) = vv;
        }
    }
    __syncthreads();   // the ONLY barrier; steps 0,1 latency hid under staging

    // ---- persistent tile loop, fully unrolled (all xv indices static) ----
    f32x4 acc[8];
    #pragma unroll
    for (int tl = 0; tl < 2; ++tl) {
        #pragma unroll
        for (int mf = 0; mf < 8; ++mf) acc[mf] = (f32x4){0.f, 0.f, 0.f, 0.f};

        #pragma unroll
        for (int ks = 0; ks < 4; ++ks) {
            const int s = tl * 4 + ks;      // global pipeline step 0..7
            // consume buffer s&1 (data for step s)
            bf16x8 bfrag;
            #pragma unroll
            for (int v = 0; v < 8; ++v) bfrag[v] = (bf16)xv[s & 1][v];
            // refill: issue step s+2 into the freed buffer (16 loads in flight)
            if (s + 2 < 8) {
                const int tl2 = (s + 2) >> 2, ks2 = (s + 2) & 3;
                #pragma unroll
                for (int v = 0; v < 8; ++v)
                    xv[s & 1][v] = xcol[tl2][(ks2 * 32 + g * 8 + v) * 16384];
            }
            const int k0 = ks * 32 + g * 8;  // sigma(g,v)=g*8+v on A and B
            #pragma unroll
            for (int mf = 0; mf < 8; ++mf) {
                const bf16x8 afrag = *(const bf16x8*)(ldsA + aoff(mf * 16 + lr, k0));
                acc[mf] = __builtin_amdgcn_mfma_f32_16x16x32_bf16(afrag, bfrag, acc[mf], 0, 0, 0);
            }
        }

        // ---- stores: D col(w)=lane&15, row(o)=g*4+r (verified layout) ----
        // 16 lanes x 4B contiguous per (mf,r); 4 o-rows per instr = 256 B.
        // Tile B's first loads are already in flight while these drain.
        #pragma unroll
        for (int mf = 0; mf < 8; ++mf) {
            #pragma unroll
            for (int r = 0; r < 4; ++r)
                outp[tl][(size_t)(mf * 16 + g * 4 + r) * 16384] = acc[mf][r];
        }
    }
}

extern "C" void kernel_launch(void* const* d_in, const int* in_sizes, int n_in,
                              void* d_out, int out_size, void* d_ws, size_t ws_size,
                              hipStream_t stream) {
    const float* x      = (const float*)d_in[0];
    const float* alphas = (const float*)d_in[1];
    // betas (d_in[2]) provably unused: contributes only to Im(y), dropped by real().
    float* out = (float*)d_out;

    dim3 grid(512);    // persistent: exactly 2 blocks/CU, 2 tiles per block
    dim3 block(512);
    hipLaunchKernelGGL(kk_freqmix_kernel, grid, block, 0, stream, x, alphas, out);
}